// Round 1
// baseline (3643.261 us; speedup 1.0000x reference)
//
#include <hip/hip_runtime.h>

#define B_   32
#define T_   2048
#define DIN  128
#define H_   256
#define DOUT 256

typedef _Float16 h2_t __attribute__((ext_vector_type(2)));

__device__ __forceinline__ float fdot2a(unsigned int a, unsigned int b, float c) {
#if defined(__has_builtin) && __has_builtin(__builtin_amdgcn_fdot2)
  return __builtin_amdgcn_fdot2(__builtin_bit_cast(h2_t, a),
                                __builtin_bit_cast(h2_t, b), c, false);
#else
  h2_t x = __builtin_bit_cast(h2_t, a), y = __builtin_bit_cast(h2_t, b);
  return c + (float)x[0] * (float)y[0] + (float)x[1] * (float)y[1];
#endif
}

// 256-long dot product: uc = 128 packed f16 pairs (register-resident column),
// hp = shared vector of 128 packed f16 pairs read as uint4 (broadcast reads).
__device__ __forceinline__ float dot256(const unsigned int* uc, const uint4* hp) {
  float a0 = 0.f, a1 = 0.f, a2 = 0.f, a3 = 0.f;
#pragma unroll
  for (int k8 = 0; k8 < 32; ++k8) {
    uint4 hq = hp[k8];
    a0 = fdot2a(uc[4 * k8 + 0], hq.x, a0);
    a1 = fdot2a(uc[4 * k8 + 1], hq.y, a1);
    a2 = fdot2a(uc[4 * k8 + 2], hq.z, a2);
    a3 = fdot2a(uc[4 * k8 + 3], hq.w, a3);
  }
  return (a0 + a1) + (a2 + a3);
}

// ---------------- Kernel 1: G = x @ [Wz|Wr|Wh] + [bz|br|bh]  (fp16 out) ----
// grid = (BT/32, 3), block = 256. Tile: 32 rows x 256 cols per block.
__global__ __launch_bounds__(256) void k_gates(
    const float* __restrict__ x,
    const float* __restrict__ Wz, const float* __restrict__ Wr,
    const float* __restrict__ Wh,
    const float* __restrict__ bz, const float* __restrict__ br,
    const float* __restrict__ bh,
    _Float16* __restrict__ Gzr,   // [BT][512] gates z,r   (lives in d_out ys region)
    _Float16* __restrict__ Gh)    // [BT][256] gate h      (lives in ws)
{
  __shared__ __align__(16) float sx[32][DIN];
  const int gate = blockIdx.y;
  const float* W = (gate == 0) ? Wz : (gate == 1) ? Wr : Wh;
  const float* bias = (gate == 0) ? bz : (gate == 1) ? br : bh;
  const int row0 = blockIdx.x * 32;
  const int tid = threadIdx.x;

  // stage x rows (contiguous 32*128 floats)
  const float4* xg = (const float4*)(x + (size_t)row0 * DIN);
  float4* sx4 = (float4*)&sx[0][0];
#pragma unroll
  for (int m = 0; m < 4; ++m) sx4[tid + 256 * m] = xg[tid + 256 * m];
  __syncthreads();

  const int j = tid;
  const float bj = bias[j];
  float acc[32];
#pragma unroll
  for (int i = 0; i < 32; ++i) acc[i] = 0.f;

#pragma unroll 2
  for (int k4 = 0; k4 < DIN / 4; ++k4) {
    float w0 = W[(size_t)(4 * k4 + 0) * H_ + j];
    float w1 = W[(size_t)(4 * k4 + 1) * H_ + j];
    float w2 = W[(size_t)(4 * k4 + 2) * H_ + j];
    float w3 = W[(size_t)(4 * k4 + 3) * H_ + j];
#pragma unroll
    for (int i = 0; i < 32; ++i) {
      float4 xv = *(const float4*)&sx[i][4 * k4];
      acc[i] = fmaf(xv.x, w0, acc[i]);
      acc[i] = fmaf(xv.y, w1, acc[i]);
      acc[i] = fmaf(xv.z, w2, acc[i]);
      acc[i] = fmaf(xv.w, w3, acc[i]);
    }
  }

  if (gate < 2) {
    _Float16* Gp = Gzr + (size_t)row0 * 512 + gate * H_ + j;
#pragma unroll
    for (int i = 0; i < 32; ++i) Gp[(size_t)i * 512] = (_Float16)(acc[i] + bj);
  } else {
    _Float16* Gp = Gh + (size_t)row0 * H_ + j;
#pragma unroll
    for (int i = 0; i < 32; ++i) Gp[(size_t)i * H_] = (_Float16)(acc[i] + bj);
  }
}

// ---------------- Kernel 2: the GRU scan. One block per batch element. -----
// 768 threads: tid<256 -> z columns, 256..511 -> r columns, 512..767 -> h cols.
// Each thread holds its 256-long U column as 128 packed fp16 pairs in VGPRs.
__global__ __launch_bounds__(768, 3) void k_scan(
    const float* __restrict__ h0,
    const float* __restrict__ Uz, const float* __restrict__ Ur,
    const float* __restrict__ Uh,
    const _Float16* __restrict__ Gzr, const _Float16* __restrict__ Gh,
    float* __restrict__ hs)
{
  __shared__ __align__(16) _Float16 h_h[H_];
  __shared__ __align__(16) _Float16 rh_h[H_];
  __shared__ float h_f[H_];
  __shared__ float z_s[H_];

  const int b = blockIdx.x;
  const int tid = threadIdx.x;
  const int g = tid >> 8;      // 0=z, 1=r, 2=h
  const int j = tid & 255;
  const float* U = (g == 0) ? Uz : (g == 1) ? Ur : Uh;

  // load U column j -> 128 packed fp16 pairs in registers
  unsigned int uc[128];
#pragma unroll
  for (int k2 = 0; k2 < 128; ++k2) {
    float a = U[(size_t)(2 * k2) * H_ + j];
    float c = U[(size_t)(2 * k2 + 1) * H_ + j];
    h2_t p;
    p[0] = (_Float16)a;
    p[1] = (_Float16)c;
    uc[k2] = __builtin_bit_cast(unsigned int, p);
  }

  if (tid < H_) {
    float h = h0[(size_t)b * H_ + tid];
    h_f[tid] = h;
    h_h[tid] = (_Float16)h;
  }
  __syncthreads();

  const _Float16* Gsrc;
  size_t gstride;
  if (g < 2) {
    Gsrc = Gzr + (size_t)b * T_ * 512 + tid;
    gstride = 512;
  } else {
    Gsrc = Gh + (size_t)b * T_ * H_ + j;
    gstride = 256;
  }
  _Float16 gnx = Gsrc[0];
  float* hsb = hs + (size_t)b * T_ * H_;

#pragma unroll 1
  for (int t = 0; t < T_; ++t) {
    float gv = (float)gnx;
    int tn = (t + 1 < T_) ? (t + 1) : t;
    gnx = Gsrc[(size_t)tn * gstride];  // prefetch next step (independent of h)

    if (tid < 512) {
      float acc = dot256(uc, (const uint4*)h_h);
      float s = 1.f / (1.f + __expf(-(gv + acc)));
      if (g == 0)
        z_s[j] = s;
      else
        rh_h[j] = (_Float16)(s * h_f[j]);
    }
    __syncthreads();

    if (tid >= 512) {
      float acc = dot256(uc, (const uint4*)rh_h);
      float xh = gv + acc;
      float e = __expf(-2.f * xh);
      float hh = 2.f / (1.f + e) - 1.f;  // tanh
      float z = z_s[j];
      float h = h_f[j];
      float hn = (1.f - z) * h + z * hh;
      h_f[j] = hn;
      h_h[j] = (_Float16)hn;
      hsb[(size_t)t * H_ + j] = hn;
    }
    __syncthreads();
  }
}

// ---------------- Kernel 3: ys = hs @ Wo + bo ------------------------------
// grid = BT/32, block = 256. Tile: 32 rows x 256 cols.
__global__ __launch_bounds__(256) void k_out(
    const float* __restrict__ hs, const float* __restrict__ Wo,
    const float* __restrict__ bo, float* __restrict__ ys)
{
  __shared__ __align__(16) float sh[32][H_];
  const int row0 = blockIdx.x * 32;
  const int tid = threadIdx.x;

  const float4* hg = (const float4*)(hs + (size_t)row0 * H_);
  float4* sh4 = (float4*)&sh[0][0];
#pragma unroll
  for (int m = 0; m < 8; ++m) sh4[tid + 256 * m] = hg[tid + 256 * m];
  __syncthreads();

  const int j = tid;
  float acc[32];
#pragma unroll
  for (int i = 0; i < 32; ++i) acc[i] = 0.f;

#pragma unroll 2
  for (int k4 = 0; k4 < H_ / 4; ++k4) {
    float w0 = Wo[(size_t)(4 * k4 + 0) * DOUT + j];
    float w1 = Wo[(size_t)(4 * k4 + 1) * DOUT + j];
    float w2 = Wo[(size_t)(4 * k4 + 2) * DOUT + j];
    float w3 = Wo[(size_t)(4 * k4 + 3) * DOUT + j];
#pragma unroll
    for (int i = 0; i < 32; ++i) {
      float4 hv = *(const float4*)&sh[i][4 * k4];
      acc[i] = fmaf(hv.x, w0, acc[i]);
      acc[i] = fmaf(hv.y, w1, acc[i]);
      acc[i] = fmaf(hv.z, w2, acc[i]);
      acc[i] = fmaf(hv.w, w3, acc[i]);
    }
  }

  const float bj = bo[j];
  float* yp = ys + (size_t)row0 * DOUT + j;
#pragma unroll
  for (int i = 0; i < 32; ++i) yp[(size_t)i * DOUT] = acc[i] + bj;
}

// ---------------------------------------------------------------------------
extern "C" void kernel_launch(void* const* d_in, const int* in_sizes, int n_in,
                              void* d_out, int out_size, void* d_ws, size_t ws_size,
                              hipStream_t stream) {
  const float* x  = (const float*)d_in[0];
  const float* h0 = (const float*)d_in[1];
  const float* Wz = (const float*)d_in[2];
  const float* Uz = (const float*)d_in[3];
  const float* bz = (const float*)d_in[4];
  const float* Wr = (const float*)d_in[5];
  const float* Ur = (const float*)d_in[6];
  const float* br = (const float*)d_in[7];
  const float* Wh = (const float*)d_in[8];
  const float* Uh = (const float*)d_in[9];
  const float* bh = (const float*)d_in[10];
  const float* Wo = (const float*)d_in[11];
  const float* bo = (const float*)d_in[12];

  float* ys = (float*)d_out;
  float* hsO = ys + (size_t)B_ * T_ * DOUT;  // second output, written by scan

  // Gz|Gr (fp16, [BT][512]) exactly fills the ys region (64 MB) which is dead
  // until k_out runs; Gh (fp16, [BT][256], 32 MB) goes in the workspace.
  _Float16* Gzr = (_Float16*)d_out;
  _Float16* Gh  = (_Float16*)d_ws;

  dim3 g1((B_ * T_) / 32, 3);
  k_gates<<<g1, 256, 0, stream>>>(x, Wz, Wr, Wh, bz, br, bh, Gzr, Gh);
  k_scan<<<B_, 768, 0, stream>>>(h0, Uz, Ur, Uh, Gzr, Gh, hsO);
  k_out<<<(B_ * T_) / 32, 256, 0, stream>>>(hsO, Wo, bo, ys);
}

// Round 2
// 3515.428 us; speedup vs baseline: 1.0364x; 1.0364x over previous
//
#include <hip/hip_runtime.h>

#define B_   32
#define T_   2048
#define DIN  128
#define H_   256
#define DOUT 256

typedef _Float16 h2_t __attribute__((ext_vector_type(2)));

__device__ __forceinline__ float fdot2a(unsigned int a, unsigned int b, float c) {
#if defined(__has_builtin) && __has_builtin(__builtin_amdgcn_fdot2)
  return __builtin_amdgcn_fdot2(__builtin_bit_cast(h2_t, a),
                                __builtin_bit_cast(h2_t, b), c, false);
#else
  h2_t x = __builtin_bit_cast(h2_t, a), y = __builtin_bit_cast(h2_t, b);
  return c + (float)x[0] * (float)y[0] + (float)x[1] * (float)y[1];
#endif
}

// 256-long dot: uc = 128 packed f16 pairs (registers), hp = 32 uint4 broadcast
__device__ __forceinline__ float dot256(const unsigned int* uc, const uint4* hp) {
  float a0 = 0.f, a1 = 0.f, a2 = 0.f, a3 = 0.f;
#pragma unroll
  for (int k8 = 0; k8 < 32; ++k8) {
    uint4 hq = hp[k8];
    a0 = fdot2a(uc[4 * k8 + 0], hq.x, a0);
    a1 = fdot2a(uc[4 * k8 + 1], hq.y, a1);
    a2 = fdot2a(uc[4 * k8 + 2], hq.z, a2);
    a3 = fdot2a(uc[4 * k8 + 3], hq.w, a3);
  }
  return (a0 + a1) + (a2 + a3);
}

// 128-long dot: uc = 64 packed pairs, hp = 16 uint4
__device__ __forceinline__ float dot128(const unsigned int* uc, const uint4* hp) {
  float a0 = 0.f, a1 = 0.f, a2 = 0.f, a3 = 0.f;
#pragma unroll
  for (int k8 = 0; k8 < 16; ++k8) {
    uint4 hq = hp[k8];
    a0 = fdot2a(uc[4 * k8 + 0], hq.x, a0);
    a1 = fdot2a(uc[4 * k8 + 1], hq.y, a1);
    a2 = fdot2a(uc[4 * k8 + 2], hq.z, a2);
    a3 = fdot2a(uc[4 * k8 + 3], hq.w, a3);
  }
  return (a0 + a1) + (a2 + a3);
}

// ---------------- Kernel 1: G = x @ [Wz|Wr|Wh] + [bz|br|bh]  (fp16 out) ----
__global__ __launch_bounds__(256) void k_gates(
    const float* __restrict__ x,
    const float* __restrict__ Wz, const float* __restrict__ Wr,
    const float* __restrict__ Wh,
    const float* __restrict__ bz, const float* __restrict__ br,
    const float* __restrict__ bh,
    _Float16* __restrict__ Gzr,   // [BT][512] gates z,r   (lives in d_out ys region)
    _Float16* __restrict__ Gh)    // [BT][256] gate h      (lives in ws)
{
  __shared__ __align__(16) float sx[32][DIN];
  const int gate = blockIdx.y;
  const float* W = (gate == 0) ? Wz : (gate == 1) ? Wr : Wh;
  const float* bias = (gate == 0) ? bz : (gate == 1) ? br : bh;
  const int row0 = blockIdx.x * 32;
  const int tid = threadIdx.x;

  const float4* xg = (const float4*)(x + (size_t)row0 * DIN);
  float4* sx4 = (float4*)&sx[0][0];
#pragma unroll
  for (int m = 0; m < 4; ++m) sx4[tid + 256 * m] = xg[tid + 256 * m];
  __syncthreads();

  const int j = tid;
  const float bj = bias[j];
  float acc[32];
#pragma unroll
  for (int i = 0; i < 32; ++i) acc[i] = 0.f;

#pragma unroll 2
  for (int k4 = 0; k4 < DIN / 4; ++k4) {
    float w0 = W[(size_t)(4 * k4 + 0) * H_ + j];
    float w1 = W[(size_t)(4 * k4 + 1) * H_ + j];
    float w2 = W[(size_t)(4 * k4 + 2) * H_ + j];
    float w3 = W[(size_t)(4 * k4 + 3) * H_ + j];
#pragma unroll
    for (int i = 0; i < 32; ++i) {
      float4 xv = *(const float4*)&sx[i][4 * k4];
      acc[i] = fmaf(xv.x, w0, acc[i]);
      acc[i] = fmaf(xv.y, w1, acc[i]);
      acc[i] = fmaf(xv.z, w2, acc[i]);
      acc[i] = fmaf(xv.w, w3, acc[i]);
    }
  }

  if (gate < 2) {
    _Float16* Gp = Gzr + (size_t)row0 * 512 + gate * H_ + j;
#pragma unroll
    for (int i = 0; i < 32; ++i) Gp[(size_t)i * 512] = (_Float16)(acc[i] + bj);
  } else {
    _Float16* Gp = Gh + (size_t)row0 * H_ + j;
#pragma unroll
    for (int i = 0; i < 32; ++i) Gp[(size_t)i * H_] = (_Float16)(acc[i] + bj);
  }
}

// ---------------- Kernel 2: GRU scan, one block (CU) per batch element -----
// 512 threads = 8 waves (2/SIMD -> 256 VGPR cap, no spill).
//   tid<256  (half=0): Uz column j (128 regs) + Uh column j, k in [0,128)   (64 regs)
//   tid>=256 (half=1): Ur column j (128 regs) + Uh column j, k in [128,256) (64 regs)
__global__ __launch_bounds__(512, 2) void k_scan(
    const float* __restrict__ h0,
    const float* __restrict__ Uz, const float* __restrict__ Ur,
    const float* __restrict__ Uh,
    const _Float16* __restrict__ Gzr, const _Float16* __restrict__ Gh,
    float* __restrict__ hs)
{
  __shared__ __align__(16) _Float16 h_h[H_];
  __shared__ __align__(16) _Float16 rh_h[H_];
  __shared__ float h_f[H_];
  __shared__ float z_s[H_];
  __shared__ float ph_s[H_];

  const int b = blockIdx.x;
  const int tid = threadIdx.x;
  const int half = tid >> 8;   // 0: z-gate + low Uh half, 1: r-gate + high Uh half
  const int j = tid & 255;

  // full column of Uz or Ur -> 128 packed fp16 pairs
  const float* Uzr = half ? Ur : Uz;
  unsigned int uzr[128];
#pragma unroll
  for (int k2 = 0; k2 < 128; ++k2) {
    float a = Uzr[(size_t)(2 * k2) * H_ + j];
    float c = Uzr[(size_t)(2 * k2 + 1) * H_ + j];
    h2_t p; p[0] = (_Float16)a; p[1] = (_Float16)c;
    uzr[k2] = __builtin_bit_cast(unsigned int, p);
  }
  // half-column of Uh -> 64 packed pairs, rows [half*128, half*128+128)
  unsigned int uh[64];
#pragma unroll
  for (int k2 = 0; k2 < 64; ++k2) {
    int k = half * 128 + 2 * k2;
    float a = Uh[(size_t)k * H_ + j];
    float c = Uh[(size_t)(k + 1) * H_ + j];
    h2_t p; p[0] = (_Float16)a; p[1] = (_Float16)c;
    uh[k2] = __builtin_bit_cast(unsigned int, p);
  }

  if (tid < H_) {
    float h = h0[(size_t)b * H_ + tid];
    h_f[tid] = h;
    h_h[tid] = (_Float16)h;
  }
  __syncthreads();

  // G pointers: half=0 threads consume Gz and Gh, half=1 threads consume Gr.
  const _Float16* Gzr_p = Gzr + (size_t)b * T_ * 512 + half * H_ + j;
  const _Float16* Gh_p  = Gh  + (size_t)b * T_ * H_ + j;
  _Float16 g_zr = Gzr_p[0];
  _Float16 g_h  = (half == 0) ? Gh_p[0] : (_Float16)0.f;

  float* hsb = hs + (size_t)b * T_ * H_;

#pragma unroll 1
  for (int t = 0; t < T_; ++t) {
    const float gv_zr = (float)g_zr;
    const float gv_h  = (float)g_h;
    const int tn = (t + 1 < T_) ? (t + 1) : t;
    g_zr = Gzr_p[(size_t)tn * 512];             // prefetch next step
    if (half == 0) g_h = Gh_p[(size_t)tn * H_];

    // phase 1: z (half 0) and r (half 1) full dots against h
    {
      float acc = dot256(uzr, (const uint4*)h_h);
      float s = 1.f / (1.f + __expf(-(gv_zr + acc)));
      if (half == 0) z_s[j] = s;
      else           rh_h[j] = (_Float16)(s * h_f[j]);
    }
    __syncthreads();

    // phase 2: h-gate half-dots against rh
    {
      float p = dot128(uh, (const uint4*)rh_h + half * 16);
      if (half == 1) ph_s[j] = p;
      __syncthreads();
      if (half == 0) {
        float xh = gv_h + p + ph_s[j];
        float e = __expf(-2.f * xh);
        float hh = 2.f / (1.f + e) - 1.f;       // tanh
        float z = z_s[j];
        float h = h_f[j];
        float hn = (1.f - z) * h + z * hh;
        h_f[j] = hn;
        h_h[j] = (_Float16)hn;
        hsb[(size_t)t * H_ + j] = hn;
      }
    }
    __syncthreads();
  }
}

// ---------------- Kernel 3: ys = hs @ Wo + bo ------------------------------
__global__ __launch_bounds__(256) void k_out(
    const float* __restrict__ hs, const float* __restrict__ Wo,
    const float* __restrict__ bo, float* __restrict__ ys)
{
  __shared__ __align__(16) float sh[32][H_];
  const int row0 = blockIdx.x * 32;
  const int tid = threadIdx.x;

  const float4* hg = (const float4*)(hs + (size_t)row0 * H_);
  float4* sh4 = (float4*)&sh[0][0];
#pragma unroll
  for (int m = 0; m < 8; ++m) sh4[tid + 256 * m] = hg[tid + 256 * m];
  __syncthreads();

  const int j = tid;
  float acc[32];
#pragma unroll
  for (int i = 0; i < 32; ++i) acc[i] = 0.f;

#pragma unroll 2
  for (int k4 = 0; k4 < H_ / 4; ++k4) {
    float w0 = Wo[(size_t)(4 * k4 + 0) * DOUT + j];
    float w1 = Wo[(size_t)(4 * k4 + 1) * DOUT + j];
    float w2 = Wo[(size_t)(4 * k4 + 2) * DOUT + j];
    float w3 = Wo[(size_t)(4 * k4 + 3) * DOUT + j];
#pragma unroll
    for (int i = 0; i < 32; ++i) {
      float4 hv = *(const float4*)&sh[i][4 * k4];
      acc[i] = fmaf(hv.x, w0, acc[i]);
      acc[i] = fmaf(hv.y, w1, acc[i]);
      acc[i] = fmaf(hv.z, w2, acc[i]);
      acc[i] = fmaf(hv.w, w3, acc[i]);
    }
  }

  const float bj = bo[j];
  float* yp = ys + (size_t)row0 * DOUT + j;
#pragma unroll
  for (int i = 0; i < 32; ++i) yp[(size_t)i * DOUT] = acc[i] + bj;
}

// ---------------------------------------------------------------------------
extern "C" void kernel_launch(void* const* d_in, const int* in_sizes, int n_in,
                              void* d_out, int out_size, void* d_ws, size_t ws_size,
                              hipStream_t stream) {
  const float* x  = (const float*)d_in[0];
  const float* h0 = (const float*)d_in[1];
  const float* Wz = (const float*)d_in[2];
  const float* Uz = (const float*)d_in[3];
  const float* bz = (const float*)d_in[4];
  const float* Wr = (const float*)d_in[5];
  const float* Ur = (const float*)d_in[6];
  const float* br = (const float*)d_in[7];
  const float* Wh = (const float*)d_in[8];
  const float* Uh = (const float*)d_in[9];
  const float* bh = (const float*)d_in[10];
  const float* Wo = (const float*)d_in[11];
  const float* bo = (const float*)d_in[12];

  float* ys = (float*)d_out;
  float* hsO = ys + (size_t)B_ * T_ * DOUT;  // second output, written by scan

  _Float16* Gzr = (_Float16*)d_out;          // 64 MB, dead until k_out
  _Float16* Gh  = (_Float16*)d_ws;           // 32 MB in workspace

  dim3 g1((B_ * T_) / 32, 3);
  k_gates<<<g1, 256, 0, stream>>>(x, Wz, Wr, Wh, bz, br, bh, Gzr, Gh);
  k_scan<<<B_, 512, 0, stream>>>(h0, Uz, Ur, Uh, Gzr, Gh, hsO);
  k_out<<<(B_ * T_) / 32, 256, 0, stream>>>(hsO, Wo, bo, ys);
}

// Round 3
// 3425.201 us; speedup vs baseline: 1.0637x; 1.0263x over previous
//
#include <hip/hip_runtime.h>

#define B_   32
#define T_   2048
#define DIN  128
#define H_   256
#define DOUT 256

typedef _Float16 h2_t __attribute__((ext_vector_type(2)));

__device__ __forceinline__ float fdot2a(unsigned int a, unsigned int b, float c) {
#if defined(__has_builtin) && __has_builtin(__builtin_amdgcn_fdot2)
  return __builtin_amdgcn_fdot2(__builtin_bit_cast(h2_t, a),
                                __builtin_bit_cast(h2_t, b), c, false);
#else
  h2_t x = __builtin_bit_cast(h2_t, a), y = __builtin_bit_cast(h2_t, b);
  return c + (float)x[0] * (float)y[0] + (float)x[1] * (float)y[1];
#endif
}

// 256-long dot: uc = 128 packed f16 pairs (registers), hp = 32 uint4 broadcast
__device__ __forceinline__ float dot256(const unsigned int* uc, const uint4* hp) {
  float a0 = 0.f, a1 = 0.f, a2 = 0.f, a3 = 0.f;
#pragma unroll
  for (int k8 = 0; k8 < 32; ++k8) {
    uint4 hq = hp[k8];
    a0 = fdot2a(uc[4 * k8 + 0], hq.x, a0);
    a1 = fdot2a(uc[4 * k8 + 1], hq.y, a1);
    a2 = fdot2a(uc[4 * k8 + 2], hq.z, a2);
    a3 = fdot2a(uc[4 * k8 + 3], hq.w, a3);
  }
  return (a0 + a1) + (a2 + a3);
}

// 128-long dot: uc = 64 packed pairs, hp = 16 uint4
__device__ __forceinline__ float dot128(const unsigned int* uc, const uint4* hp) {
  float a0 = 0.f, a1 = 0.f, a2 = 0.f, a3 = 0.f;
#pragma unroll
  for (int k8 = 0; k8 < 16; ++k8) {
    uint4 hq = hp[k8];
    a0 = fdot2a(uc[4 * k8 + 0], hq.x, a0);
    a1 = fdot2a(uc[4 * k8 + 1], hq.y, a1);
    a2 = fdot2a(uc[4 * k8 + 2], hq.z, a2);
    a3 = fdot2a(uc[4 * k8 + 3], hq.w, a3);
  }
  return (a0 + a1) + (a2 + a3);
}

// ---------------- Kernel 1: G = x @ [Wz|Wr|Wh] + [bz|br|bh]  (fp16 out) ----
__global__ __launch_bounds__(256) void k_gates(
    const float* __restrict__ x,
    const float* __restrict__ Wz, const float* __restrict__ Wr,
    const float* __restrict__ Wh,
    const float* __restrict__ bz, const float* __restrict__ br,
    const float* __restrict__ bh,
    _Float16* __restrict__ Gzr,   // [BT][512] gates z,r   (lives in d_out ys region)
    _Float16* __restrict__ Gh)    // [BT][256] gate h      (lives in ws)
{
  __shared__ __align__(16) float sx[32][DIN];
  const int gate = blockIdx.y;
  const float* W = (gate == 0) ? Wz : (gate == 1) ? Wr : Wh;
  const float* bias = (gate == 0) ? bz : (gate == 1) ? br : bh;
  const int row0 = blockIdx.x * 32;
  const int tid = threadIdx.x;

  const float4* xg = (const float4*)(x + (size_t)row0 * DIN);
  float4* sx4 = (float4*)&sx[0][0];
#pragma unroll
  for (int m = 0; m < 4; ++m) sx4[tid + 256 * m] = xg[tid + 256 * m];
  __syncthreads();

  const int j = tid;
  const float bj = bias[j];
  float acc[32];
#pragma unroll
  for (int i = 0; i < 32; ++i) acc[i] = 0.f;

#pragma unroll 2
  for (int k4 = 0; k4 < DIN / 4; ++k4) {
    float w0 = W[(size_t)(4 * k4 + 0) * H_ + j];
    float w1 = W[(size_t)(4 * k4 + 1) * H_ + j];
    float w2 = W[(size_t)(4 * k4 + 2) * H_ + j];
    float w3 = W[(size_t)(4 * k4 + 3) * H_ + j];
#pragma unroll
    for (int i = 0; i < 32; ++i) {
      float4 xv = *(const float4*)&sx[i][4 * k4];
      acc[i] = fmaf(xv.x, w0, acc[i]);
      acc[i] = fmaf(xv.y, w1, acc[i]);
      acc[i] = fmaf(xv.z, w2, acc[i]);
      acc[i] = fmaf(xv.w, w3, acc[i]);
    }
  }

  if (gate < 2) {
    _Float16* Gp = Gzr + (size_t)row0 * 512 + gate * H_ + j;
#pragma unroll
    for (int i = 0; i < 32; ++i) Gp[(size_t)i * 512] = (_Float16)(acc[i] + bj);
  } else {
    _Float16* Gp = Gh + (size_t)row0 * H_ + j;
#pragma unroll
    for (int i = 0; i < 32; ++i) Gp[(size_t)i * H_] = (_Float16)(acc[i] + bj);
  }
}

// ---------------- Kernel 2: GRU scan, one block (CU) per batch element -----
// 512 threads = 8 waves, exactly 2 waves/SIMD -> 256-VGPR budget.
//   tid<256  (half=0): Uz column j (128 regs) + Uh column j, k in [0,128)   (64 regs)
//   tid>=256 (half=1): Ur column j (128 regs) + Uh column j, k in [128,256) (64 regs)
// U values are PINNED into VGPRs via empty asm (redefinition) so the
// register allocator cannot rematerialize them as in-loop global reloads.
__global__
__attribute__((amdgpu_flat_work_group_size(512, 512), amdgpu_waves_per_eu(2, 2)))
void k_scan(
    const float* __restrict__ h0,
    const float* __restrict__ Uz, const float* __restrict__ Ur,
    const float* __restrict__ Uh,
    const _Float16* __restrict__ Gzr, const _Float16* __restrict__ Gh,
    float* __restrict__ hs)
{
  __shared__ __align__(16) _Float16 h_h[H_];
  __shared__ __align__(16) _Float16 rh_h[H_];
  __shared__ float h_f[H_];
  __shared__ float z_s[H_];
  __shared__ float ph_s[H_];

  const int b = blockIdx.x;
  const int tid = threadIdx.x;
  const int half = tid >> 8;   // 0: z-gate + low Uh half, 1: r-gate + high Uh half
  const int j = tid & 255;

  // full column of Uz or Ur -> 128 packed fp16 pairs
  const float* Uzr = half ? Ur : Uz;
  unsigned int uzr[128];
#pragma unroll
  for (int k2 = 0; k2 < 128; ++k2) {
    float a = Uzr[(size_t)(2 * k2) * H_ + j];
    float c = Uzr[(size_t)(2 * k2 + 1) * H_ + j];
    h2_t p; p[0] = (_Float16)a; p[1] = (_Float16)c;
    uzr[k2] = __builtin_bit_cast(unsigned int, p);
  }
  // half-column of Uh -> 64 packed pairs, rows [half*128, half*128+128)
  unsigned int uh[64];
#pragma unroll
  for (int k2 = 0; k2 < 64; ++k2) {
    int k = half * 128 + 2 * k2;
    float a = Uh[(size_t)k * H_ + j];
    float c = Uh[(size_t)(k + 1) * H_ + j];
    h2_t p; p[0] = (_Float16)a; p[1] = (_Float16)c;
    uh[k2] = __builtin_bit_cast(unsigned int, p);
  }

  // Pin: force every U word to be VGPR-resident and non-rematerializable.
#pragma unroll
  for (int k2 = 0; k2 < 128; ++k2) asm volatile("" : "+v"(uzr[k2]));
#pragma unroll
  for (int k2 = 0; k2 < 64; ++k2) asm volatile("" : "+v"(uh[k2]));

  if (tid < H_) {
    float h = h0[(size_t)b * H_ + tid];
    h_f[tid] = h;
    h_h[tid] = (_Float16)h;
  }
  __syncthreads();

  // G pointers: half=0 threads consume Gz and Gh, half=1 threads consume Gr.
  const _Float16* Gzr_p = Gzr + (size_t)b * T_ * 512 + half * H_ + j;
  const _Float16* Gh_p  = Gh  + (size_t)b * T_ * H_ + j;
  _Float16 g_zr = Gzr_p[0];
  _Float16 g_h  = (half == 0) ? Gh_p[0] : (_Float16)0.f;

  float* hsb = hs + (size_t)b * T_ * H_;

#pragma unroll 1
  for (int t = 0; t < T_; ++t) {
    const float gv_zr = (float)g_zr;
    const float gv_h  = (float)g_h;
    const int tn = (t + 1 < T_) ? (t + 1) : t;
    g_zr = Gzr_p[(size_t)tn * 512];             // prefetch next step
    if (half == 0) g_h = Gh_p[(size_t)tn * H_];

    // phase 1: z (half 0) and r (half 1) full dots against h
    {
      float acc = dot256(uzr, (const uint4*)h_h);
      float s = 1.f / (1.f + __expf(-(gv_zr + acc)));
      if (half == 0) z_s[j] = s;
      else           rh_h[j] = (_Float16)(s * h_f[j]);
    }
    __syncthreads();

    // phase 2: h-gate half-dots against rh
    {
      float p = dot128(uh, (const uint4*)rh_h + half * 16);
      if (half == 1) ph_s[j] = p;
      __syncthreads();
      if (half == 0) {
        float xh = gv_h + p + ph_s[j];
        float e = __expf(-2.f * xh);
        float hh = 2.f / (1.f + e) - 1.f;       // tanh
        float z = z_s[j];
        float h = h_f[j];
        float hn = (1.f - z) * h + z * hh;
        h_f[j] = hn;
        h_h[j] = (_Float16)hn;
        hsb[(size_t)t * H_ + j] = hn;
      }
    }
    __syncthreads();
  }
}

// ---------------- Kernel 3: ys = hs @ Wo + bo ------------------------------
__global__ __launch_bounds__(256) void k_out(
    const float* __restrict__ hs, const float* __restrict__ Wo,
    const float* __restrict__ bo, float* __restrict__ ys)
{
  __shared__ __align__(16) float sh[32][H_];
  const int row0 = blockIdx.x * 32;
  const int tid = threadIdx.x;

  const float4* hg = (const float4*)(hs + (size_t)row0 * H_);
  float4* sh4 = (float4*)&sh[0][0];
#pragma unroll
  for (int m = 0; m < 8; ++m) sh4[tid + 256 * m] = hg[tid + 256 * m];
  __syncthreads();

  const int j = tid;
  float acc[32];
#pragma unroll
  for (int i = 0; i < 32; ++i) acc[i] = 0.f;

#pragma unroll 2
  for (int k4 = 0; k4 < H_ / 4; ++k4) {
    float w0 = Wo[(size_t)(4 * k4 + 0) * DOUT + j];
    float w1 = Wo[(size_t)(4 * k4 + 1) * DOUT + j];
    float w2 = Wo[(size_t)(4 * k4 + 2) * DOUT + j];
    float w3 = Wo[(size_t)(4 * k4 + 3) * DOUT + j];
#pragma unroll
    for (int i = 0; i < 32; ++i) {
      float4 hv = *(const float4*)&sh[i][4 * k4];
      acc[i] = fmaf(hv.x, w0, acc[i]);
      acc[i] = fmaf(hv.y, w1, acc[i]);
      acc[i] = fmaf(hv.z, w2, acc[i]);
      acc[i] = fmaf(hv.w, w3, acc[i]);
    }
  }

  const float bj = bo[j];
  float* yp = ys + (size_t)row0 * DOUT + j;
#pragma unroll
  for (int i = 0; i < 32; ++i) yp[(size_t)i * DOUT] = acc[i] + bj;
}

// ---------------------------------------------------------------------------
extern "C" void kernel_launch(void* const* d_in, const int* in_sizes, int n_in,
                              void* d_out, int out_size, void* d_ws, size_t ws_size,
                              hipStream_t stream) {
  const float* x  = (const float*)d_in[0];
  const float* h0 = (const float*)d_in[1];
  const float* Wz = (const float*)d_in[2];
  const float* Uz = (const float*)d_in[3];
  const float* bz = (const float*)d_in[4];
  const float* Wr = (const float*)d_in[5];
  const float* Ur = (const float*)d_in[6];
  const float* br = (const float*)d_in[7];
  const float* Wh = (const float*)d_in[8];
  const float* Uh = (const float*)d_in[9];
  const float* bh = (const float*)d_in[10];
  const float* Wo = (const float*)d_in[11];
  const float* bo = (const float*)d_in[12];

  float* ys = (float*)d_out;
  float* hsO = ys + (size_t)B_ * T_ * DOUT;  // second output, written by scan

  _Float16* Gzr = (_Float16*)d_out;          // 64 MB, dead until k_out
  _Float16* Gh  = (_Float16*)d_ws;           // 32 MB in workspace

  dim3 g1((B_ * T_) / 32, 3);
  k_gates<<<g1, 256, 0, stream>>>(x, Wz, Wr, Wh, bz, br, bh, Gzr, Gh);
  k_scan<<<B_, 512, 0, stream>>>(h0, Uz, Ur, Uh, Gzr, Gh, hsO);
  k_out<<<(B_ * T_) / 32, 256, 0, stream>>>(hsO, Wo, bo, ys);
}